// Round 5
// baseline (942.693 us; speedup 1.0000x reference)
//
#include <hip/hip_runtime.h>
#include <hip/hip_bf16.h>

typedef __attribute__((ext_vector_type(8))) short short8;    // 8 bf16 = 32x32x16 A/B frag
typedef __attribute__((ext_vector_type(16))) float f32x16;   // 32x32 C/D frag

#define BLOCK 512      // 8 waves
#define GTILE 32       // edges per wave-tile (one 32x32 MFMA M-tile)

// W region: logical [row][boff] with 256-B rows, XOR ((row&15)<<4) (verified r4).
__device__ __forceinline__ int swz16(int row, int boff) {
    return (row << 8) + (boff ^ ((row & 15) << 4));
}
// Z region: logical [row][boff] with 128-B rows (one K-half), XOR ((row&7)<<4).
__device__ __forceinline__ int swzH(int row, int boff) {
    return (row << 7) + (boff ^ ((row & 7) << 4));
}

// ---------------- pre-pass: f32 -> bf16 tables in workspace ----------------
__global__ __launch_bounds__(256) void cvt_bf16_kernel(
    const float* __restrict__ a, const float* __restrict__ b,
    __hip_bfloat16* __restrict__ oa, __hip_bfloat16* __restrict__ ob, int n)
{
    const int i = blockIdx.x * blockDim.x + threadIdx.x;
    const int stride = gridDim.x * blockDim.x;
    const float4* a4 = (const float4*)a;
    const float4* b4 = (const float4*)b;
    const int n8 = n >> 3;
    for (int j = i; j < n8; j += stride) {
        float4 x0 = a4[2 * j], x1 = a4[2 * j + 1];
        float4 y0 = b4[2 * j], y1 = b4[2 * j + 1];
        union { __hip_bfloat16 h[8]; uint4 u; } pa, pb;
        pa.h[0]=__float2bfloat16(x0.x); pa.h[1]=__float2bfloat16(x0.y);
        pa.h[2]=__float2bfloat16(x0.z); pa.h[3]=__float2bfloat16(x0.w);
        pa.h[4]=__float2bfloat16(x1.x); pa.h[5]=__float2bfloat16(x1.y);
        pa.h[6]=__float2bfloat16(x1.z); pa.h[7]=__float2bfloat16(x1.w);
        pb.h[0]=__float2bfloat16(y0.x); pb.h[1]=__float2bfloat16(y0.y);
        pb.h[2]=__float2bfloat16(y0.z); pb.h[3]=__float2bfloat16(y0.w);
        pb.h[4]=__float2bfloat16(y1.x); pb.h[5]=__float2bfloat16(y1.y);
        pb.h[6]=__float2bfloat16(y1.z); pb.h[7]=__float2bfloat16(y1.w);
        ((uint4*)oa)[j] = pa.u;
        ((uint4*)ob)[j] = pb.u;
    }
    for (int j = (n8 << 3) + i; j < n; j += stride) {
        oa[j] = __float2bfloat16(a[j]);
        ob[j] = __float2bfloat16(b[j]);
    }
}

// ---------------- fused edge-MLP, barrier-free waves, K-phased Z ----------------
// 8 independent waves/block. W1^T shared in LDS (32 KB, read-only after one
// barrier). Each wave: private 4 KB Z holding ONE K-half of its 32-edge tile;
// two write->read phases per tile (in-order per-wave DS makes the overwrite
// safe without barriers). 2 blocks/CU -> 16 waves/CU.
template<bool BF16G>
__global__ __launch_bounds__(BLOCK, 4) void edge_mlp_kernel(
    const float* __restrict__ srcf, const float* __restrict__ dstf,
    const __hip_bfloat16* __restrict__ srcb, const __hip_bfloat16* __restrict__ dstb,
    const int*   __restrict__ eli,
    const float* __restrict__ W1, const float* __restrict__ b1,
    const float* __restrict__ W2, const float* __restrict__ b2,
    float* __restrict__ out, int E)
{
    __shared__ __align__(16) char lds[65536];   // [0,32K)=W1^T, [32K,64K)=8x4K Z

    const int tid  = threadIdx.x;
    const int lane = tid & 63;
    const int w    = tid >> 6;    // 0..7
    const int n32  = lane & 31;   // MFMA row/col-in-tile
    const int half = lane >> 5;   // k-half-within-phase selector
    const int ch   = lane & 15;   // 16-B chunk (k-slice) this lane gathered
    const int rq   = lane >> 4;   // 0..3: row-within-quad
    const int myp  = ch >> 3;     // which K-phase this lane's chunk feeds
    const int cl   = ch & 7;      // chunk within its phase

    // ---- prologue: stage W1^T (bf16, swizzled)
    for (int idx = tid; idx < 128 * 128; idx += BLOCK) {
        int k = idx >> 7, n = idx & 127;                 // coalesced along n
        *(__hip_bfloat16*)(lds + swz16(n, k * 2)) = __float2bfloat16(W1[idx]);
    }
    // per-wave index-width probe (no shared flag -> no cross-wave race)
    int probe = eli[2 * (lane & 31) + 1];
    unsigned long long bl = __ballot(lane < 32 && probe != 0);
    const int i64f = (bl == 0ull) ? 1 : 0;
    __syncthreads();   // the ONLY barrier

    char* zb = lds + 32768 + (w << 12);   // this wave's private 4 KB

    float b1s[4], w2s[4];
    #pragma unroll
    for (int cb = 0; cb < 4; ++cb) {
        b1s[cb] = b1[cb * 32 + n32];
        w2s[cb] = W2[cb * 32 + n32];
    }
    const float bias2 = b2[0];

    const int ngroups = (E + GTILE - 1) / GTILE;
    const int step = gridDim.x * 8;
    int g = blockIdx.x * 8 + w;
    if (g >= ngroups) return;   // safe: no barriers after this point

    // lane-parallel index vector: lanes 0-31 = src idx, 32-63 = dst idx
    auto idxload = [&](int gg) -> int {
        gg = gg < ngroups ? gg : ngroups - 1;
        int e = gg * GTILE + n32; if (e >= E) e = E - 1;
        size_t off = half ? (size_t)E + (size_t)e : (size_t)e;
        return i64f ? eli[2 * off] : eli[off];
    };

    short8 sv[8], dv[8];   // prefetched rows (next tile): lane holds 8 rows x its chunk
    auto loadRows = [&](int iv) {
        const short8* s8 = (const short8*)srcb;
        const short8* d8 = (const short8*)dstb;
        #pragma unroll
        for (int i = 0; i < 8; ++i) {
            int R = i * 4 + rq;                  // per instr: 4 rows x 256B contiguous
            int r = __shfl(iv, R, 64);
            int c = __shfl(iv, 32 + R, 64);
            sv[i] = s8[(size_t)r * 16 + ch];
            dv[i] = d8[(size_t)c * 16 + ch];
        }
    };
    // write this lane's products for phase p into zb (only lanes with myp==p)
    auto writePhase = [&](int p) {
        if (myp == p) {
            #pragma unroll
            for (int i = 0; i < 8; ++i) {
                int R = i * 4 + rq;
                union { __hip_bfloat16 h[8]; short8 v; } pr;
                #pragma unroll
                for (int j = 0; j < 8; ++j) {
                    float fs = __bfloat162float(((const __hip_bfloat16*)&sv[i])[j]);
                    float fd = __bfloat162float(((const __hip_bfloat16*)&dv[i])[j]);
                    pr.h[j] = __float2bfloat16(fs * fd);
                }
                *(short8*)(zb + swzH(R, cl * 16)) = pr.v;
            }
        }
    };

    int iv_cur = idxload(g);
    float4 svf[8], dvf[8];   // f32 fallback staging
    auto loadRowsF = [&](int iv) {
        const float4* s4 = (const float4*)srcf;
        const float4* d4 = (const float4*)dstf;
        #pragma unroll
        for (int i = 0; i < 8; ++i) {
            int R = i * 4 + rq;
            int r = __shfl(iv, R, 64);
            int c = __shfl(iv, 32 + R, 64);
            svf[i] = s4[(size_t)r * 32 + ch * 2];
            dvf[i] = d4[(size_t)r == (size_t)r ? (size_t)c * 32 + ch * 2 : 0];
        }
    };
    auto writePhaseF = [&](int p) {
        if (myp == p) {
            #pragma unroll
            for (int i = 0; i < 8; ++i) {
                int R = i * 4 + rq;
                union { __hip_bfloat16 h[4]; uint2 u; } q;
                float4 a0 = svf[i], c0 = dvf[i];
                q.h[0] = __float2bfloat16(a0.x * c0.x);
                q.h[1] = __float2bfloat16(a0.y * c0.y);
                q.h[2] = __float2bfloat16(a0.z * c0.z);
                q.h[3] = __float2bfloat16(a0.w * c0.w);
                *(uint2*)(zb + swzH(R, cl * 16 + (ch & 1) * 0)) = q.u;   // 8B: chunk=8 floats? no
            }
        }
    };
    // NOTE: f32 fallback uses half-chunk (32B=8 floats) per lane: cl*16 covers 8 bf16 ✓

    if constexpr (BF16G) loadRows(iv_cur);
    else                 loadRowsF(iv_cur);
    int iv_nxt = idxload(g + step);

    for (; g < ngroups; g += step) {
        asm volatile("" ::: "memory");   // order next phase-0 writes after prior epilogue reads

        f32x16 acc[4];
        #pragma unroll
        for (int cb = 0; cb < 4; ++cb)
            #pragma unroll
            for (int j = 0; j < 16; ++j)
                acc[cb][j] = 0.f;

        // ---- phase 0: stage K=0..63, MFMA kk=0..3
        if constexpr (BF16G) writePhase(0); else writePhaseF(0);
        asm volatile("" ::: "memory");
        __builtin_amdgcn_s_setprio(1);
        #pragma unroll
        for (int kk = 0; kk < 4; ++kk) {
            short8 af = *(const short8*)(zb + swzH(n32, kk * 32 + half * 16));
            #pragma unroll
            for (int cb = 0; cb < 4; ++cb) {
                short8 bf = *(const short8*)(lds + swz16(cb * 32 + n32,
                                                         kk * 32 + half * 16));
                acc[cb] = __builtin_amdgcn_mfma_f32_32x32x16_bf16(af, bf, acc[cb], 0, 0, 0);
            }
        }
        __builtin_amdgcn_s_setprio(0);
        asm volatile("" ::: "memory");

        // ---- phase 1: stage K=64..127 (in-order DS: prior reads serviced first)
        if constexpr (BF16G) writePhase(1); else writePhaseF(1);

        // T14: sv/dv consumed -> issue next tile's gather; hides under MFMA+epilogue
        {
            int iv2 = idxload(g + 2 * step);
            if constexpr (BF16G) loadRows(iv_nxt); else loadRowsF(iv_nxt);
            iv_nxt = iv2;
        }
        asm volatile("" ::: "memory");
        __builtin_amdgcn_s_setprio(1);
        #pragma unroll
        for (int kk = 0; kk < 4; ++kk) {
            short8 af = *(const short8*)(zb + swzH(n32, kk * 32 + half * 16));
            #pragma unroll
            for (int cb = 0; cb < 4; ++cb) {
                short8 bf = *(const short8*)(lds + swz16(cb * 32 + n32,
                                                         (kk + 4) * 32 + half * 16));
                acc[cb] = __builtin_amdgcn_mfma_f32_32x32x16_bf16(af, bf, acc[cb], 0, 0, 0);
            }
        }
        __builtin_amdgcn_s_setprio(0);
        asm volatile("" ::: "memory");

        // ---- epilogue: relu + W2-dot; transpose partials through zb (Z consumed)
        // lane holds hidden col n32 (per cb); D row = (r&3)+8*(r>>2)+4*half.
        #pragma unroll
        for (int r = 0; r < 16; ++r) {
            float p = 0.f;
            #pragma unroll
            for (int cb = 0; cb < 4; ++cb) {
                float h = acc[cb][r] + b1s[cb];
                h = fmaxf(h, 0.f);
                p = fmaf(h, w2s[cb], p);
            }
            int R = (r & 3) + 8 * (r >> 2) + 4 * half;
            *(float*)(zb + ((R << 7) + ((n32 << 2) ^ ((R & 7) << 4)))) = p;
        }
        asm volatile("" ::: "memory");
        float tot = 0.f;
        #pragma unroll
        for (int j = 0; j < 4; ++j) {
            float4 v = *(const float4*)(zb + ((n32 << 7) +
                         ((half * 64 + j * 16) ^ ((n32 & 7) << 4))));
            tot += v.x + v.y + v.z + v.w;
        }
        tot += __shfl_xor(tot, 32, 64);   // combine the two 16-partial halves
        int e = g * GTILE + n32;
        if (half == 0 && e < E)
            __builtin_nontemporal_store(tot + bias2, &out[e]);
    }
}

extern "C" void kernel_launch(void* const* d_in, const int* in_sizes, int n_in,
                              void* d_out, int out_size, void* d_ws, size_t ws_size,
                              hipStream_t stream) {
    const float* src = (const float*)d_in[0];
    const float* dst = (const float*)d_in[1];
    const int*   eli = (const int*)d_in[2];
    const float* W1  = (const float*)d_in[3];
    const float* b1  = (const float*)d_in[4];
    const float* W2  = (const float*)d_in[5];
    const float* b2  = (const float*)d_in[6];
    float* out = (float*)d_out;

    const int E = in_sizes[2] / 2;
    const int nsrc = in_sizes[0];
    const size_t need = (size_t)(in_sizes[0] + in_sizes[1]) * sizeof(__hip_bfloat16);
    const int ngroups = (E + GTILE - 1) / GTILE;
    int nblocks = (ngroups + 7) / 8;
    int grid = nblocks < 512 ? nblocks : 512;   // 2 blocks/CU resident, grid-stride

    if (ws_size >= need) {
        __hip_bfloat16* srcb = (__hip_bfloat16*)d_ws;
        __hip_bfloat16* dstb = srcb + nsrc;
        cvt_bf16_kernel<<<dim3(2048), dim3(256), 0, stream>>>(src, dst, srcb, dstb, nsrc);
        edge_mlp_kernel<true><<<dim3(grid), dim3(BLOCK), 0, stream>>>(
            src, dst, srcb, dstb, eli, W1, b1, W2, b2, out, E);
    } else {
        edge_mlp_kernel<false><<<dim3(grid), dim3(BLOCK), 0, stream>>>(
            src, dst, (const __hip_bfloat16*)nullptr, (const __hip_bfloat16*)nullptr,
            eli, W1, b1, W2, b2, out, E);
    }
}

// Round 6
// 795.802 us; speedup vs baseline: 1.1846x; 1.1846x over previous
//
#include <hip/hip_runtime.h>
#include <hip/hip_bf16.h>

typedef __attribute__((ext_vector_type(8))) short short8;    // 8 bf16 = 32x32x16 A/B frag
typedef __attribute__((ext_vector_type(16))) float f32x16;   // 32x32 C/D frag

#define BLOCK 256      // 4 waves
#define GTILE 32       // edges per wave-tile (one 32x32 MFMA M-tile)

// W region: logical [row][boff] with 256-B rows, XOR ((row&15)<<4) (verified r4/r5).
__device__ __forceinline__ int swz16(int row, int boff) {
    return (row << 8) + (boff ^ ((row & 15) << 4));
}
// Z region: logical [row][boff] with 128-B rows (one K-half), XOR ((row&7)<<4).
__device__ __forceinline__ int swzH(int row, int boff) {
    return (row << 7) + (boff ^ ((row & 7) << 4));
}

// ---------------- pre-pass: f32 -> bf16 tables in workspace ----------------
__global__ __launch_bounds__(256) void cvt_bf16_kernel(
    const float* __restrict__ a, const float* __restrict__ b,
    __hip_bfloat16* __restrict__ oa, __hip_bfloat16* __restrict__ ob, int n)
{
    const int i = blockIdx.x * blockDim.x + threadIdx.x;
    const int stride = gridDim.x * blockDim.x;
    const float4* a4 = (const float4*)a;
    const float4* b4 = (const float4*)b;
    const int n8 = n >> 3;
    for (int j = i; j < n8; j += stride) {
        float4 x0 = a4[2 * j], x1 = a4[2 * j + 1];
        float4 y0 = b4[2 * j], y1 = b4[2 * j + 1];
        union { __hip_bfloat16 h[8]; uint4 u; } pa, pb;
        pa.h[0]=__float2bfloat16(x0.x); pa.h[1]=__float2bfloat16(x0.y);
        pa.h[2]=__float2bfloat16(x0.z); pa.h[3]=__float2bfloat16(x0.w);
        pa.h[4]=__float2bfloat16(x1.x); pa.h[5]=__float2bfloat16(x1.y);
        pa.h[6]=__float2bfloat16(x1.z); pa.h[7]=__float2bfloat16(x1.w);
        pb.h[0]=__float2bfloat16(y0.x); pb.h[1]=__float2bfloat16(y0.y);
        pb.h[2]=__float2bfloat16(y0.z); pb.h[3]=__float2bfloat16(y0.w);
        pb.h[4]=__float2bfloat16(y1.x); pb.h[5]=__float2bfloat16(y1.y);
        pb.h[6]=__float2bfloat16(y1.z); pb.h[7]=__float2bfloat16(y1.w);
        ((uint4*)oa)[j] = pa.u;
        ((uint4*)ob)[j] = pb.u;
    }
    for (int j = (n8 << 3) + i; j < n; j += stride) {
        oa[j] = __float2bfloat16(a[j]);
        ob[j] = __float2bfloat16(b[j]);
    }
}

// ---------------- fused edge-MLP, barrier-free waves, K-phased Z ----------------
// 4 independent waves/block. W1^T shared in LDS (32 KB, read-only after one
// barrier). Each wave: private 4 KB Z holding ONE K-half of its 32-edge tile;
// two write->read phases per tile (same-wave in-order DS + compiler fences
// make the overwrite safe without barriers; validated r5). LDS 48 KB ->
// 3 blocks/CU = 12 waves/CU. VGPR cap 170 (no spill; r4 measured 124).
template<bool BF16G>
__global__ __launch_bounds__(BLOCK, 3) void edge_mlp_kernel(
    const float* __restrict__ srcf, const float* __restrict__ dstf,
    const __hip_bfloat16* __restrict__ srcb, const __hip_bfloat16* __restrict__ dstb,
    const int*   __restrict__ eli,
    const float* __restrict__ W1, const float* __restrict__ b1,
    const float* __restrict__ W2, const float* __restrict__ b2,
    float* __restrict__ out, int E)
{
    __shared__ __align__(16) char lds[49152];   // [0,32K)=W1^T, [32K,48K)=4x4K Z

    const int tid  = threadIdx.x;
    const int lane = tid & 63;
    const int w    = tid >> 6;    // 0..3
    const int n32  = lane & 31;   // MFMA row/col-in-tile
    const int half = lane >> 5;   // k-half-within-phase selector
    const int ch   = lane & 15;   // 16-B chunk (k-slice) this lane gathered
    const int rq   = lane >> 4;   // 0..3: row-within-quad
    const int myp  = ch >> 3;     // which K-phase this lane's chunk feeds
    const int cl   = ch & 7;      // chunk within its phase

    // ---- prologue: stage W1^T (bf16, swizzled)
    for (int idx = tid; idx < 128 * 128; idx += BLOCK) {
        int k = idx >> 7, n = idx & 127;                 // coalesced along n
        *(__hip_bfloat16*)(lds + swz16(n, k * 2)) = __float2bfloat16(W1[idx]);
    }
    // per-wave index-width probe
    int probe = eli[2 * (lane & 31) + 1];
    unsigned long long bl = __ballot(lane < 32 && probe != 0);
    const int i64f = (bl == 0ull) ? 1 : 0;
    __syncthreads();   // the ONLY barrier

    char* zb = lds + 32768 + (w << 12);   // this wave's private 4 KB

    float b1s[4], w2s[4];
    #pragma unroll
    for (int cb = 0; cb < 4; ++cb) {
        b1s[cb] = b1[cb * 32 + n32];
        w2s[cb] = W2[cb * 32 + n32];
    }
    const float bias2 = b2[0];

    const int ngroups = (E + GTILE - 1) / GTILE;
    const int step = gridDim.x * 4;
    int g = blockIdx.x * 4 + w;
    if (g >= ngroups) return;   // safe: no barriers after this point

    // lane-parallel index vector: lanes 0-31 = src idx, 32-63 = dst idx
    auto idxload = [&](int gg) -> int {
        gg = gg < ngroups ? gg : ngroups - 1;
        int e = gg * GTILE + n32; if (e >= E) e = E - 1;
        size_t off = half ? (size_t)E + (size_t)e : (size_t)e;
        return i64f ? eli[2 * off] : eli[off];
    };

    short8 sv[8], dv[8];   // prefetched rows (next tile): lane holds 8 rows x its 16B chunk
    auto loadRows = [&](int iv) {
        const short8* s8 = (const short8*)srcb;
        const short8* d8 = (const short8*)dstb;
        #pragma unroll
        for (int i = 0; i < 8; ++i) {
            int R = i * 4 + rq;                  // per instr: 4 rows x 256B contiguous
            int r = __shfl(iv, R, 64);
            int c = __shfl(iv, 32 + R, 64);
            sv[i] = s8[(size_t)r * 16 + ch];
            dv[i] = d8[(size_t)c * 16 + ch];
        }
    };
    // write this lane's products for phase p into zb (only lanes with myp==p)
    auto writePhase = [&](int p) {
        if (myp == p) {
            #pragma unroll
            for (int i = 0; i < 8; ++i) {
                int R = i * 4 + rq;
                union { __hip_bfloat16 h[8]; short8 v; } pr;
                #pragma unroll
                for (int j = 0; j < 8; ++j) {
                    float fs = __bfloat162float(((const __hip_bfloat16*)&sv[i])[j]);
                    float fd = __bfloat162float(((const __hip_bfloat16*)&dv[i])[j]);
                    pr.h[j] = __float2bfloat16(fs * fd);
                }
                *(short8*)(zb + swzH(R, cl * 16)) = pr.v;
            }
        }
    };
    // f32 fallback: load + product + write for phase p, no prefetch regs.
    // lane's chunk = floats [p*64 + cl*8, +8) of its rows.
    auto stagePhaseF = [&](int iv, int p) {
        if (myp == p) {
            const float4* s4 = (const float4*)srcf;
            const float4* d4 = (const float4*)dstf;
            #pragma unroll
            for (int i = 0; i < 8; ++i) {
                int R = i * 4 + rq;
                int r = __shfl(iv, R, 64);
                int c = __shfl(iv, 32 + R, 64);
                float4 a0 = s4[(size_t)r * 32 + p * 16 + cl * 2];
                float4 a1 = s4[(size_t)r * 32 + p * 16 + cl * 2 + 1];
                float4 c0 = d4[(size_t)c * 32 + p * 16 + cl * 2];
                float4 c1 = d4[(size_t)c * 32 + p * 16 + cl * 2 + 1];
                union { __hip_bfloat16 h[8]; short8 v; } pr;
                pr.h[0] = __float2bfloat16(a0.x * c0.x);
                pr.h[1] = __float2bfloat16(a0.y * c0.y);
                pr.h[2] = __float2bfloat16(a0.z * c0.z);
                pr.h[3] = __float2bfloat16(a0.w * c0.w);
                pr.h[4] = __float2bfloat16(a1.x * c1.x);
                pr.h[5] = __float2bfloat16(a1.y * c1.y);
                pr.h[6] = __float2bfloat16(a1.z * c1.z);
                pr.h[7] = __float2bfloat16(a1.w * c1.w);
                *(short8*)(zb + swzH(R, cl * 16)) = pr.v;
            }
        }
    };

    int iv_cur = idxload(g);
    if constexpr (BF16G) loadRows(iv_cur);
    int iv_nxt = idxload(g + step);

    for (; g < ngroups; g += step) {
        asm volatile("" ::: "memory");   // order phase-0 writes after prior epilogue reads

        f32x16 acc[4];
        #pragma unroll
        for (int cb = 0; cb < 4; ++cb)
            #pragma unroll
            for (int j = 0; j < 16; ++j)
                acc[cb][j] = 0.f;

        // ---- phase 0: stage K=0..63, MFMA with B kk=0..3
        if constexpr (BF16G) writePhase(0); else stagePhaseF(iv_cur, 0);
        asm volatile("" ::: "memory");
        __builtin_amdgcn_s_setprio(1);
        #pragma unroll
        for (int kk = 0; kk < 4; ++kk) {
            short8 af = *(const short8*)(zb + swzH(n32, kk * 32 + half * 16));
            #pragma unroll
            for (int cb = 0; cb < 4; ++cb) {
                short8 bf = *(const short8*)(lds + swz16(cb * 32 + n32,
                                                         kk * 32 + half * 16));
                acc[cb] = __builtin_amdgcn_mfma_f32_32x32x16_bf16(af, bf, acc[cb], 0, 0, 0);
            }
        }
        __builtin_amdgcn_s_setprio(0);
        asm volatile("" ::: "memory");

        // ---- phase 1: stage K=64..127 (same-wave in-order DS after phase-0 reads)
        if constexpr (BF16G) writePhase(1); else stagePhaseF(iv_cur, 1);

        // T14: sv/dv consumed -> issue next tile's gather; hides under MFMA+epilogue
        if constexpr (BF16G) {
            int iv2 = idxload(g + 2 * step);
            loadRows(iv_nxt);
            iv_cur = iv_nxt;     // (unused in bf16 path, kept for symmetry)
            iv_nxt = iv2;
        } else {
            iv_cur = iv_nxt;
            iv_nxt = idxload(g + 2 * step);
        }
        asm volatile("" ::: "memory");
        __builtin_amdgcn_s_setprio(1);
        #pragma unroll
        for (int kk = 0; kk < 4; ++kk) {
            short8 af = *(const short8*)(zb + swzH(n32, kk * 32 + half * 16));
            #pragma unroll
            for (int cb = 0; cb < 4; ++cb) {
                short8 bf = *(const short8*)(lds + swz16(cb * 32 + n32,
                                                         (kk + 4) * 32 + half * 16));
                acc[cb] = __builtin_amdgcn_mfma_f32_32x32x16_bf16(af, bf, acc[cb], 0, 0, 0);
            }
        }
        __builtin_amdgcn_s_setprio(0);
        asm volatile("" ::: "memory");

        // ---- epilogue: relu + W2-dot; transpose partials through zb (Z consumed)
        // lane holds hidden col n32 (per cb); D row = (r&3)+8*(r>>2)+4*half.
        #pragma unroll
        for (int r = 0; r < 16; ++r) {
            float p = 0.f;
            #pragma unroll
            for (int cb = 0; cb < 4; ++cb) {
                float h = acc[cb][r] + b1s[cb];
                h = fmaxf(h, 0.f);
                p = fmaf(h, w2s[cb], p);
            }
            int R = (r & 3) + 8 * (r >> 2) + 4 * half;
            *(float*)(zb + ((R << 7) + ((n32 << 2) ^ ((R & 7) << 4)))) = p;
        }
        asm volatile("" ::: "memory");
        float tot = 0.f;
        #pragma unroll
        for (int j = 0; j < 4; ++j) {
            float4 v = *(const float4*)(zb + ((n32 << 7) +
                         ((half * 64 + j * 16) ^ ((n32 & 7) << 4))));
            tot += v.x + v.y + v.z + v.w;
        }
        tot += __shfl_xor(tot, 32, 64);   // combine the two 16-partial halves
        int e = g * GTILE + n32;
        if (half == 0 && e < E)
            __builtin_nontemporal_store(tot + bias2, &out[e]);
    }
}

extern "C" void kernel_launch(void* const* d_in, const int* in_sizes, int n_in,
                              void* d_out, int out_size, void* d_ws, size_t ws_size,
                              hipStream_t stream) {
    const float* src = (const float*)d_in[0];
    const float* dst = (const float*)d_in[1];
    const int*   eli = (const int*)d_in[2];
    const float* W1  = (const float*)d_in[3];
    const float* b1  = (const float*)d_in[4];
    const float* W2  = (const float*)d_in[5];
    const float* b2  = (const float*)d_in[6];
    float* out = (float*)d_out;

    const int E = in_sizes[2] / 2;
    const int nsrc = in_sizes[0];
    const size_t need = (size_t)(in_sizes[0] + in_sizes[1]) * sizeof(__hip_bfloat16);
    const int ngroups = (E + GTILE - 1) / GTILE;
    int nblocks = (ngroups + 3) / 4;
    int grid = nblocks < 768 ? nblocks : 768;   // 3 blocks/CU resident, grid-stride

    if (ws_size >= need) {
        __hip_bfloat16* srcb = (__hip_bfloat16*)d_ws;
        __hip_bfloat16* dstb = srcb + nsrc;
        cvt_bf16_kernel<<<dim3(2048), dim3(256), 0, stream>>>(src, dst, srcb, dstb, nsrc);
        edge_mlp_kernel<true><<<dim3(grid), dim3(BLOCK), 0, stream>>>(
            src, dst, srcb, dstb, eli, W1, b1, W2, b2, out, E);
    } else {
        edge_mlp_kernel<false><<<dim3(grid), dim3(BLOCK), 0, stream>>>(
            src, dst, (const __hip_bfloat16*)nullptr, (const __hip_bfloat16*)nullptr,
            eli, W1, b1, W2, b2, out, E);
    }
}

// Round 7
// 186.659 us; speedup vs baseline: 5.0504x; 4.2634x over previous
//
#include <hip/hip_runtime.h>
#include <hip/hip_bf16.h>

typedef __attribute__((ext_vector_type(8))) short short8;    // 8 bf16 = 32x32x16 A/B frag
typedef __attribute__((ext_vector_type(16))) float f32x16;   // 32x32 C/D frag

#define BLOCK 256      // 4 waves
#define GTILE 32       // edges per wave-tile (one 32x32 MFMA M-tile)

// W region: logical [row][boff] with 256-B rows, XOR ((row&15)<<4) (verified r4-r6).
__device__ __forceinline__ int swz16(int row, int boff) {
    return (row << 8) + (boff ^ ((row & 15) << 4));
}
// Z region: logical [row][boff] with 128-B rows (one K-half), XOR ((row&7)<<4).
__device__ __forceinline__ int swzH(int row, int boff) {
    return (row << 7) + (boff ^ ((row & 7) << 4));
}

// ---------------- pre-pass: f32 -> bf16 tables in workspace ----------------
__global__ __launch_bounds__(256) void cvt_bf16_kernel(
    const float* __restrict__ a, const float* __restrict__ b,
    __hip_bfloat16* __restrict__ oa, __hip_bfloat16* __restrict__ ob, int n)
{
    const int i = blockIdx.x * blockDim.x + threadIdx.x;
    const int stride = gridDim.x * blockDim.x;
    const float4* a4 = (const float4*)a;
    const float4* b4 = (const float4*)b;
    const int n8 = n >> 3;
    for (int j = i; j < n8; j += stride) {
        float4 x0 = a4[2 * j], x1 = a4[2 * j + 1];
        float4 y0 = b4[2 * j], y1 = b4[2 * j + 1];
        union { __hip_bfloat16 h[8]; uint4 u; } pa, pb;
        pa.h[0]=__float2bfloat16(x0.x); pa.h[1]=__float2bfloat16(x0.y);
        pa.h[2]=__float2bfloat16(x0.z); pa.h[3]=__float2bfloat16(x0.w);
        pa.h[4]=__float2bfloat16(x1.x); pa.h[5]=__float2bfloat16(x1.y);
        pa.h[6]=__float2bfloat16(x1.z); pa.h[7]=__float2bfloat16(x1.w);
        pb.h[0]=__float2bfloat16(y0.x); pb.h[1]=__float2bfloat16(y0.y);
        pb.h[2]=__float2bfloat16(y0.z); pb.h[3]=__float2bfloat16(y0.w);
        pb.h[4]=__float2bfloat16(y1.x); pb.h[5]=__float2bfloat16(y1.y);
        pb.h[6]=__float2bfloat16(y1.z); pb.h[7]=__float2bfloat16(y1.w);
        ((uint4*)oa)[j] = pa.u;
        ((uint4*)ob)[j] = pb.u;
    }
    for (int j = (n8 << 3) + i; j < n; j += stride) {
        oa[j] = __float2bfloat16(a[j]);
        ob[j] = __float2bfloat16(b[j]);
    }
}

// ---------------- fused edge-MLP, barrier-free waves, K-phased Z ----------------
// 4 independent waves/block. W1^T shared in LDS (32 KB). Each wave: private
// 4 KB Z holding ONE K-half (128 B/row) of its 32-edge tile; two write->read
// phases per tile. Per phase ALL lanes gather only that phase's half-rows
// (sv/dv = 32 VGPR), so acc(64) never coexists with a 64-VGPR stage buffer:
// peak live ~130 < cap 168 -> no spill (r6's failure mode eliminated).
// LDS 48 KB -> 3 blocks/CU = 12 waves/CU.
template<bool BF16G>
__global__ __launch_bounds__(BLOCK, 3) void edge_mlp_kernel(
    const float* __restrict__ srcf, const float* __restrict__ dstf,
    const __hip_bfloat16* __restrict__ srcb, const __hip_bfloat16* __restrict__ dstb,
    const int*   __restrict__ eli,
    const float* __restrict__ W1, const float* __restrict__ b1,
    const float* __restrict__ W2, const float* __restrict__ b2,
    float* __restrict__ out, int E)
{
    __shared__ __align__(16) char lds[49152];   // [0,32K)=W1^T, [32K,48K)=4x4K Z

    const int tid  = threadIdx.x;
    const int lane = tid & 63;
    const int w    = tid >> 6;    // 0..3
    const int n32  = lane & 31;   // MFMA row/col-in-tile
    const int half = lane >> 5;   // k-half-within-phase selector
    const int rq8  = lane >> 3;   // 0..7: half-row-within-octet
    const int cl   = lane & 7;    // 16-B chunk within a 128-B half-row

    // ---- prologue: stage W1^T (bf16, swizzled)
    for (int idx = tid; idx < 128 * 128; idx += BLOCK) {
        int k = idx >> 7, n = idx & 127;                 // coalesced along n
        *(__hip_bfloat16*)(lds + swz16(n, k * 2)) = __float2bfloat16(W1[idx]);
    }
    // per-wave index-width probe
    int probe = eli[2 * (lane & 31) + 1];
    unsigned long long bl = __ballot(lane < 32 && probe != 0);
    const int i64f = (bl == 0ull) ? 1 : 0;
    __syncthreads();   // the ONLY barrier

    char* zb = lds + 32768 + (w << 12);   // this wave's private 4 KB

    float b1s[4], w2s[4];
    #pragma unroll
    for (int cb = 0; cb < 4; ++cb) {
        b1s[cb] = b1[cb * 32 + n32];
        w2s[cb] = W2[cb * 32 + n32];
    }
    const float bias2 = b2[0];

    const int ngroups = (E + GTILE - 1) / GTILE;
    const int step = gridDim.x * 4;
    int g = blockIdx.x * 4 + w;
    if (g >= ngroups) return;   // safe: no barriers after this point

    // lane-parallel index vector: lanes 0-31 = src idx, 32-63 = dst idx
    auto idxload = [&](int gg) -> int {
        gg = gg < ngroups ? gg : ngroups - 1;
        int e = gg * GTILE + n32; if (e >= E) e = E - 1;
        size_t off = half ? (size_t)E + (size_t)e : (size_t)e;
        return i64f ? eli[2 * off] : eli[off];
    };

    // one phase's rows: 32 edges x 128-B half-row for src and dst = 32 VGPR
    short8 sv[4], dv[4];
    auto loadP = [&](int iv, int p) {
        const short8* s8 = (const short8*)srcb;   // 16 chunks per 256-B row
        const short8* d8 = (const short8*)dstb;
        #pragma unroll
        for (int i = 0; i < 4; ++i) {
            int R = i * 8 + rq8;                  // per instr: 8 half-rows x 128B contiguous
            int r = __shfl(iv, R, 64);
            int c = __shfl(iv, 32 + R, 64);
            sv[i] = s8[(size_t)r * 16 + p * 8 + cl];
            dv[i] = d8[(size_t)c * 16 + p * 8 + cl];
        }
    };
    auto writeP = [&]() {
        #pragma unroll
        for (int i = 0; i < 4; ++i) {
            int R = i * 8 + rq8;
            union { __hip_bfloat16 h[8]; short8 v; } pr;
            #pragma unroll
            for (int j = 0; j < 8; ++j) {
                float fs = __bfloat162float(((const __hip_bfloat16*)&sv[i])[j]);
                float fd = __bfloat162float(((const __hip_bfloat16*)&dv[i])[j]);
                pr.h[j] = __float2bfloat16(fs * fd);
            }
            *(short8*)(zb + swzH(R, cl * 16)) = pr.v;
        }
    };
    // f32 fallback: blocking load+product+write of one phase (no prefetch regs)
    auto stagePhaseF = [&](int iv, int p) {
        const float4* s4 = (const float4*)srcf;
        const float4* d4 = (const float4*)dstf;
        #pragma unroll
        for (int i = 0; i < 4; ++i) {
            int R = i * 8 + rq8;
            int r = __shfl(iv, R, 64);
            int c = __shfl(iv, 32 + R, 64);
            float4 a0 = s4[(size_t)r * 32 + p * 16 + cl * 2];
            float4 a1 = s4[(size_t)r * 32 + p * 16 + cl * 2 + 1];
            float4 c0 = d4[(size_t)c * 32 + p * 16 + cl * 2];
            float4 c1 = d4[(size_t)c * 32 + p * 16 + cl * 2 + 1];
            union { __hip_bfloat16 h[8]; short8 v; } pr;
            pr.h[0] = __float2bfloat16(a0.x * c0.x);
            pr.h[1] = __float2bfloat16(a0.y * c0.y);
            pr.h[2] = __float2bfloat16(a0.z * c0.z);
            pr.h[3] = __float2bfloat16(a0.w * c0.w);
            pr.h[4] = __float2bfloat16(a1.x * c1.x);
            pr.h[5] = __float2bfloat16(a1.y * c1.y);
            pr.h[6] = __float2bfloat16(a1.z * c1.z);
            pr.h[7] = __float2bfloat16(a1.w * c1.w);
            *(short8*)(zb + swzH(R, cl * 16)) = pr.v;
        }
    };

    int iv_cur = idxload(g);
    if constexpr (BF16G) loadP(iv_cur, 0);     // tile-0 phase-0 rows
    int iv_nxt = idxload(g + step);

    for (; g < ngroups; g += step) {
        asm volatile("" ::: "memory");   // order phase-0 writes after prior epilogue reads

        f32x16 acc[4];
        #pragma unroll
        for (int cb = 0; cb < 4; ++cb)
            #pragma unroll
            for (int j = 0; j < 16; ++j)
                acc[cb][j] = 0.f;

        // ---- phase 0: stage K=0..63; then issue phase-1 gather (hides under MFMA0)
        if constexpr (BF16G) { writeP(); loadP(iv_cur, 1); }
        else                 stagePhaseF(iv_cur, 0);
        asm volatile("" ::: "memory");
        __builtin_amdgcn_s_setprio(1);
        #pragma unroll
        for (int kk = 0; kk < 4; ++kk) {
            short8 af = *(const short8*)(zb + swzH(n32, kk * 32 + half * 16));
            #pragma unroll
            for (int cb = 0; cb < 4; ++cb) {
                short8 bf = *(const short8*)(lds + swz16(cb * 32 + n32,
                                                         kk * 32 + half * 16));
                acc[cb] = __builtin_amdgcn_mfma_f32_32x32x16_bf16(af, bf, acc[cb], 0, 0, 0);
            }
        }
        __builtin_amdgcn_s_setprio(0);
        asm volatile("" ::: "memory");

        // ---- phase 1: stage K=64..127; then issue next tile's phase-0 gather
        if constexpr (BF16G) {
            writeP();
            loadP(iv_nxt, 0);
            iv_cur = iv_nxt;
            iv_nxt = idxload(g + 2 * step);
        } else {
            stagePhaseF(iv_cur, 1);
            iv_cur = iv_nxt;
            iv_nxt = idxload(g + 2 * step);
        }
        asm volatile("" ::: "memory");
        __builtin_amdgcn_s_setprio(1);
        #pragma unroll
        for (int kk = 0; kk < 4; ++kk) {
            short8 af = *(const short8*)(zb + swzH(n32, kk * 32 + half * 16));
            #pragma unroll
            for (int cb = 0; cb < 4; ++cb) {
                short8 bf = *(const short8*)(lds + swz16(cb * 32 + n32,
                                                         (kk + 4) * 32 + half * 16));
                acc[cb] = __builtin_amdgcn_mfma_f32_32x32x16_bf16(af, bf, acc[cb], 0, 0, 0);
            }
        }
        __builtin_amdgcn_s_setprio(0);
        asm volatile("" ::: "memory");

        // ---- epilogue: relu + W2-dot; transpose partials through zb (Z consumed)
        // lane holds hidden col n32 (per cb); D row = (r&3)+8*(r>>2)+4*half.
        #pragma unroll
        for (int r = 0; r < 16; ++r) {
            float p = 0.f;
            #pragma unroll
            for (int cb = 0; cb < 4; ++cb) {
                float h = acc[cb][r] + b1s[cb];
                h = fmaxf(h, 0.f);
                p = fmaf(h, w2s[cb], p);
            }
            int R = (r & 3) + 8 * (r >> 2) + 4 * half;
            *(float*)(zb + ((R << 7) + ((n32 << 2) ^ ((R & 7) << 4)))) = p;
        }
        asm volatile("" ::: "memory");
        float tot = 0.f;
        #pragma unroll
        for (int j = 0; j < 4; ++j) {
            float4 v = *(const float4*)(zb + ((n32 << 7) +
                         ((half * 64 + j * 16) ^ ((n32 & 7) << 4))));
            tot += v.x + v.y + v.z + v.w;
        }
        tot += __shfl_xor(tot, 32, 64);   // combine the two 16-partial halves
        int e = g * GTILE + n32;
        if (half == 0 && e < E)
            __builtin_nontemporal_store(tot + bias2, &out[e]);
    }
}

extern "C" void kernel_launch(void* const* d_in, const int* in_sizes, int n_in,
                              void* d_out, int out_size, void* d_ws, size_t ws_size,
                              hipStream_t stream) {
    const float* src = (const float*)d_in[0];
    const float* dst = (const float*)d_in[1];
    const int*   eli = (const int*)d_in[2];
    const float* W1  = (const float*)d_in[3];
    const float* b1  = (const float*)d_in[4];
    const float* W2  = (const float*)d_in[5];
    const float* b2  = (const float*)d_in[6];
    float* out = (float*)d_out;

    const int E = in_sizes[2] / 2;
    const int nsrc = in_sizes[0];
    const size_t need = (size_t)(in_sizes[0] + in_sizes[1]) * sizeof(__hip_bfloat16);
    const int ngroups = (E + GTILE - 1) / GTILE;
    int nblocks = (ngroups + 3) / 4;
    int grid = nblocks < 768 ? nblocks : 768;   // 3 blocks/CU resident, grid-stride

    if (ws_size >= need) {
        __hip_bfloat16* srcb = (__hip_bfloat16*)d_ws;
        __hip_bfloat16* dstb = srcb + nsrc;
        cvt_bf16_kernel<<<dim3(2048), dim3(256), 0, stream>>>(src, dst, srcb, dstb, nsrc);
        edge_mlp_kernel<true><<<dim3(grid), dim3(BLOCK), 0, stream>>>(
            src, dst, srcb, dstb, eli, W1, b1, W2, b2, out, E);
    } else {
        edge_mlp_kernel<false><<<dim3(grid), dim3(BLOCK), 0, stream>>>(
            src, dst, (const __hip_bfloat16*)nullptr, (const __hip_bfloat16*)nullptr,
            eli, W1, b1, W2, b2, out, E);
    }
}

// Round 8
// 177.975 us; speedup vs baseline: 5.2968x; 1.0488x over previous
//
#include <hip/hip_runtime.h>
#include <hip/hip_bf16.h>

typedef __attribute__((ext_vector_type(8))) short short8;   // 8 bf16 = 16x16x32 A/B frag
typedef __attribute__((ext_vector_type(4))) float f32x4;    // 16x16 C/D frag

#define BLOCK 256      // 4 waves
#define GTILE 16       // edges per wave-tile (one 16x16 MFMA M-tile)

// W region: logical [row][boff], 256-B rows, XOR ((row&15)<<4) (verified r4-r7).
__device__ __forceinline__ int swz16(int row, int boff) {
    return (row << 8) + (boff ^ ((row & 15) << 4));
}
// Z region: logical [halfrow][boff], 128-B rows, XOR ((row&7)<<4) (verified r4-r7).
__device__ __forceinline__ int swzH(int row, int boff) {
    return (row << 7) + (boff ^ ((row & 7) << 4));
}

// ---------------- pre-pass: f32 -> bf16 tables in workspace ----------------
__global__ __launch_bounds__(256) void cvt_bf16_kernel(
    const float* __restrict__ a, const float* __restrict__ b,
    __hip_bfloat16* __restrict__ oa, __hip_bfloat16* __restrict__ ob, int n)
{
    const int i = blockIdx.x * blockDim.x + threadIdx.x;
    const int stride = gridDim.x * blockDim.x;
    const float4* a4 = (const float4*)a;
    const float4* b4 = (const float4*)b;
    const int n8 = n >> 3;
    for (int j = i; j < n8; j += stride) {
        float4 x0 = a4[2 * j], x1 = a4[2 * j + 1];
        float4 y0 = b4[2 * j], y1 = b4[2 * j + 1];
        union { __hip_bfloat16 h[8]; uint4 u; } pa, pb;
        pa.h[0]=__float2bfloat16(x0.x); pa.h[1]=__float2bfloat16(x0.y);
        pa.h[2]=__float2bfloat16(x0.z); pa.h[3]=__float2bfloat16(x0.w);
        pa.h[4]=__float2bfloat16(x1.x); pa.h[5]=__float2bfloat16(x1.y);
        pa.h[6]=__float2bfloat16(x1.z); pa.h[7]=__float2bfloat16(x1.w);
        pb.h[0]=__float2bfloat16(y0.x); pb.h[1]=__float2bfloat16(y0.y);
        pb.h[2]=__float2bfloat16(y0.z); pb.h[3]=__float2bfloat16(y0.w);
        pb.h[4]=__float2bfloat16(y1.x); pb.h[5]=__float2bfloat16(y1.y);
        pb.h[6]=__float2bfloat16(y1.z); pb.h[7]=__float2bfloat16(y1.w);
        ((uint4*)oa)[j] = pa.u;
        ((uint4*)ob)[j] = pb.u;
    }
    for (int j = (n8 << 3) + i; j < n; j += stride) {
        oa[j] = __float2bfloat16(a[j]);
        ob[j] = __float2bfloat16(b[j]);
    }
}

// ---------------- fused edge-MLP: barrier-free waves, distance-2 prefetch ----------------
// 4 independent waves/block. W1^T shared in LDS (32 KB). Each wave: private
// 4 KB Z = one 16-edge tile ([32 halfrows][128 B], swzH). Two register
// prefetch buffers (A/B) hold full 256-B rows of tiles t+1 and t+2; each
// buffer is 32 VGPR, acc is 32 VGPR (16x16 MFMA) -> peak live ~135 < cap 168.
// Loop unrolled 2x so buffer naming is static (no dynamic reg indexing).
// LDS 48 KB -> 3 blocks/CU = 12 waves/CU; gather cover = 2 full tiles.
template<bool BF16G>
__global__ __launch_bounds__(BLOCK, 3) void edge_mlp_kernel(
    const float* __restrict__ srcf, const float* __restrict__ dstf,
    const __hip_bfloat16* __restrict__ srcb, const __hip_bfloat16* __restrict__ dstb,
    const int*   __restrict__ eli,
    const float* __restrict__ W1, const float* __restrict__ b1,
    const float* __restrict__ W2, const float* __restrict__ b2,
    float* __restrict__ out, int E)
{
    __shared__ __align__(16) char lds[49152];   // [0,32K)=W1^T, [32K,48K)=4x4K Z

    const int tid  = threadIdx.x;
    const int lane = tid & 63;
    const int w    = tid >> 6;    // 0..3
    const int rr   = lane & 15;   // MFMA row/col-in-tile
    const int kgrp = lane >> 4;   // 0..3 (k-group for 16x16x32 frags)
    const int rq8  = lane >> 3;   // 0..7: halfrow-within-octet (staging)
    const int cl   = lane & 7;    // 16-B chunk within a 128-B halfrow

    // ---- prologue: stage W1^T (bf16, swizzled)
    for (int idx = tid; idx < 128 * 128; idx += BLOCK) {
        int k = idx >> 7, n = idx & 127;                 // coalesced along n
        *(__hip_bfloat16*)(lds + swz16(n, k * 2)) = __float2bfloat16(W1[idx]);
    }
    // per-wave index-width probe
    int probe = eli[2 * (lane & 31) + 1];
    unsigned long long bl = __ballot(lane < 32 && probe != 0);
    const int i64f = (bl == 0ull) ? 1 : 0;
    __syncthreads();   // the ONLY barrier

    char* zb = lds + 32768 + (w << 12);   // this wave's private 4 KB

    float b1s[8], w2s[8];
    #pragma unroll
    for (int cb = 0; cb < 8; ++cb) {
        b1s[cb] = b1[cb * 16 + rr];
        w2s[cb] = W2[cb * 16 + rr];
    }
    const float bias2 = b2[0];

    const int ngroups = (E + GTILE - 1) / GTILE;
    const int step = gridDim.x * 4;
    int g = blockIdx.x * 4 + w;
    if (g >= ngroups) return;   // safe: no barriers after this point

    // lane-parallel index vector: lanes 0-15 = src ids, 32-47 = dst ids
    auto idxload = [&](int gg) -> int {
        gg = gg < ngroups ? gg : ngroups - 1;
        int e = gg * GTILE + rr; if (e >= E) e = E - 1;
        size_t off = (lane < 32) ? (size_t)e : (size_t)E + (size_t)e;
        return i64f ? eli[2 * off] : eli[off];
    };

    // load one tile's rows (16 edges x 256 B src+dst) into a 32-VGPR buffer
    // pair; per instr: 4 distinct rows x 256 B fully contiguous (cache-friendly).
    auto loadT = [&](int iv, short8 (&s)[4], short8 (&d)[4]) {
        const short8* s8 = (const short8*)srcb;   // 16 chunks per 256-B row
        const short8* d8 = (const short8*)dstb;
        #pragma unroll
        for (int i = 0; i < 4; ++i) {
            int hr = i * 8 + rq8;                 // halfrow 0..31
            int e  = hr >> 1, h = hr & 1;
            int r = __shfl(iv, e, 64);
            int c = __shfl(iv, 32 + e, 64);
            s[i] = s8[(size_t)r * 16 + h * 8 + cl];
            d[i] = d8[(size_t)c * 16 + h * 8 + cl];
        }
    };
    // product -> bf16 -> swizzled Z
    auto writeT = [&](const short8 (&s)[4], const short8 (&d)[4]) {
        #pragma unroll
        for (int i = 0; i < 4; ++i) {
            int hr = i * 8 + rq8;
            union { __hip_bfloat16 h[8]; short8 v; } pr;
            #pragma unroll
            for (int j = 0; j < 8; ++j) {
                float fs = __bfloat162float(((const __hip_bfloat16*)&s[i])[j]);
                float fd = __bfloat162float(((const __hip_bfloat16*)&d[i])[j]);
                pr.h[j] = __float2bfloat16(fs * fd);
            }
            *(short8*)(zb + swzH(hr, cl * 16)) = pr.v;
        }
    };
    // f32 fallback: blocking load+product+write of one tile
    auto stageF = [&](int iv) {
        const float4* s4 = (const float4*)srcf;
        const float4* d4 = (const float4*)dstf;
        #pragma unroll
        for (int i = 0; i < 4; ++i) {
            int hr = i * 8 + rq8;
            int e  = hr >> 1, h = hr & 1;
            int r = __shfl(iv, e, 64);
            int c = __shfl(iv, 32 + e, 64);
            float4 a0 = s4[(size_t)r * 32 + h * 16 + cl * 2];
            float4 a1 = s4[(size_t)r * 32 + h * 16 + cl * 2 + 1];
            float4 c0 = d4[(size_t)c * 32 + h * 16 + cl * 2];
            float4 c1 = d4[(size_t)c * 32 + h * 16 + cl * 2 + 1];
            union { __hip_bfloat16 hh[8]; short8 v; } pr;
            pr.hh[0] = __float2bfloat16(a0.x * c0.x);
            pr.hh[1] = __float2bfloat16(a0.y * c0.y);
            pr.hh[2] = __float2bfloat16(a0.z * c0.z);
            pr.hh[3] = __float2bfloat16(a0.w * c0.w);
            pr.hh[4] = __float2bfloat16(a1.x * c1.x);
            pr.hh[5] = __float2bfloat16(a1.y * c1.y);
            pr.hh[6] = __float2bfloat16(a1.z * c1.z);
            pr.hh[7] = __float2bfloat16(a1.w * c1.w);
            *(short8*)(zb + swzH(hr, cl * 16)) = pr.v;
        }
    };

    // compute + epilogue on the tile currently in zb
    auto compute = [&](int gg) {
        f32x4 acc[8];
        #pragma unroll
        for (int cb = 0; cb < 8; ++cb) acc[cb] = (f32x4){0.f, 0.f, 0.f, 0.f};
        __builtin_amdgcn_s_setprio(1);
        #pragma unroll
        for (int kk = 0; kk < 4; ++kk) {
            // A: row=rr, k = kk*32 + kgrp*8 + j  ->  halfrow rr*2+(kk>>1)
            short8 af = *(const short8*)(zb + swzH(rr * 2 + (kk >> 1),
                                                   (kk & 1) * 64 + kgrp * 16));
            #pragma unroll
            for (int cb = 0; cb < 8; ++cb) {
                short8 bf = *(const short8*)(lds + swz16(cb * 16 + rr,
                                                         kk * 64 + kgrp * 16));
                acc[cb] = __builtin_amdgcn_mfma_f32_16x16x32_bf16(af, bf, acc[cb], 0, 0, 0);
            }
        }
        __builtin_amdgcn_s_setprio(0);
        // epilogue: bias+relu+W2 dot over 128 hidden; reduce across rr lanes
        #pragma unroll
        for (int r = 0; r < 4; ++r) {
            float p = 0.f;
            #pragma unroll
            for (int cb = 0; cb < 8; ++cb) {
                float h = acc[cb][r] + b1s[cb];
                h = fmaxf(h, 0.f);
                p = fmaf(h, w2s[cb], p);
            }
            p += __shfl_xor(p, 1, 64);
            p += __shfl_xor(p, 2, 64);
            p += __shfl_xor(p, 4, 64);
            p += __shfl_xor(p, 8, 64);
            int e = gg * GTILE + kgrp * 4 + r;
            if (rr == 0 && e < E)
                __builtin_nontemporal_store(p + bias2, &out[e]);
        }
    };

    if constexpr (BF16G) {
        short8 svA[4], dvA[4], svB[4], dvB[4];
        int iv0 = idxload(g);
        int iv1 = idxload(g + step);
        loadT(iv0, svA, dvA);                 // tile t   -> buffer A
        loadT(iv1, svB, dvB);                 // tile t+1 -> buffer B
        int iv2 = idxload(g + 2 * step);      // ids for tile t+2

        while (true) {
            // ---- body A
            asm volatile("" ::: "memory");
            writeT(svA, dvA);                 // consume A (waits its loads only)
            loadT(iv2, svA, dvA);             // refill A with tile g+2
            iv2 = idxload(g + 3 * step);
            asm volatile("" ::: "memory");
            compute(g);
            g += step; if (g >= ngroups) break;

            // ---- body B
            asm volatile("" ::: "memory");
            writeT(svB, dvB);
            loadT(iv2, svB, dvB);
            iv2 = idxload(g + 3 * step);
            asm volatile("" ::: "memory");
            compute(g);
            g += step; if (g >= ngroups) break;
        }
    } else {
        for (; g < ngroups; g += step) {
            asm volatile("" ::: "memory");
            int iv = idxload(g);
            stageF(iv);
            asm volatile("" ::: "memory");
            compute(g);
        }
    }
}

extern "C" void kernel_launch(void* const* d_in, const int* in_sizes, int n_in,
                              void* d_out, int out_size, void* d_ws, size_t ws_size,
                              hipStream_t stream) {
    const float* src = (const float*)d_in[0];
    const float* dst = (const float*)d_in[1];
    const int*   eli = (const int*)d_in[2];
    const float* W1  = (const float*)d_in[3];
    const float* b1  = (const float*)d_in[4];
    const float* W2  = (const float*)d_in[5];
    const float* b2  = (const float*)d_in[6];
    float* out = (float*)d_out;

    const int E = in_sizes[2] / 2;
    const int nsrc = in_sizes[0];
    const size_t need = (size_t)(in_sizes[0] + in_sizes[1]) * sizeof(__hip_bfloat16);
    const int ngroups = (E + GTILE - 1) / GTILE;
    int nblocks = (ngroups + 3) / 4;
    int grid = nblocks < 768 ? nblocks : 768;   // 3 blocks/CU resident, grid-stride

    if (ws_size >= need) {
        __hip_bfloat16* srcb = (__hip_bfloat16*)d_ws;
        __hip_bfloat16* dstb = srcb + nsrc;
        cvt_bf16_kernel<<<dim3(2048), dim3(256), 0, stream>>>(src, dst, srcb, dstb, nsrc);
        edge_mlp_kernel<true><<<dim3(grid), dim3(BLOCK), 0, stream>>>(
            src, dst, srcb, dstb, eli, W1, b1, W2, b2, out, E);
    } else {
        edge_mlp_kernel<false><<<dim3(grid), dim3(BLOCK), 0, stream>>>(
            src, dst, (const __hip_bfloat16*)nullptr, (const __hip_bfloat16*)nullptr,
            eli, W1, b1, W2, b2, out, E);
    }
}